// Round 6
// baseline (163.755 us; speedup 1.0000x reference)
//
#include <hip/hip_runtime.h>
#include <math.h>

#ifndef M_PI
#define M_PI 3.14159265358979323846
#endif

#define NSAMP 32768
#define MHALF 16384
#define TWO_PI_F 6.2831853071795864f
#define PSTRIDE 1089   // plane stride in float2; 1089&15==1 spreads planes across bank pairs

__device__ __forceinline__ double dsig(double x) { return 1.0 / (1.0 + exp(-x)); }

// ---------------------------------------------------------------------------
// Kernel 1: per-batch parameter decode (fp64 to match the np/f64 reference).
// Emits per-oscillator phase step as Q0.64 fixed point (u64).
// ---------------------------------------------------------------------------
__global__ __launch_bounds__(128) void prep_kernel(
    const float* __restrict__ packed, const float* __restrict__ freqs,
    unsigned long long* __restrict__ step, float* __restrict__ env,
    float* __restrict__ amp, float* __restrict__ fenv)
{
    int b = blockIdx.x;
    int t = threadIdx.x;  // 0..127
    const float* pk = packed + b * 464;
    __shared__ double sh_num[128];
    __shared__ double sh_den[128];
    __shared__ double amp_d[128];

    double e_t = exp(dsig((double)pk[t]));
    sh_den[t] = e_t;
    sh_num[t] = e_t * (double)freqs[t];

    double av = dsig((double)pk[256 + t]) * 2.0 - 1.0;
    amp_d[t] = av;
    amp[b * 128 + t] = (float)av;

    if (t < 64) fenv[b * 64 + t] = (float)dsig((double)pk[400 + t]);
    __syncthreads();

    for (int off = 64; off > 0; off >>= 1) {
        if (t < off) { sh_den[t] += sh_den[t + off]; sh_num[t] += sh_num[t + off]; }
        __syncthreads();
    }

    if (t < 8) {
        const double NYQ = 11025.0;
        const double MIN_F0 = 40.0 / NYQ;
        const double MAX_F0 = 3000.0 / NYQ;
        const double F0_SPAN = MAX_F0 - MIN_F0;
        double f0 = sh_num[0] / sh_den[0];
        double F = f0 * NYQ;
        double G = MIN_F0 + F * F0_SPAN;
        double oscf = G * (double)(t + 1);
        double r = oscf / NYQ * M_PI;          // radians / sample
        double rv = r / (2.0 * M_PI);          // revolutions / sample
        rv -= floor(rv);
        step[b * 8 + t] = (unsigned long long)(rv * 18446744073709551616.0);

        double ha = dsig((double)pk[384 + t]);
        double hd = 0.9 + dsig((double)pk[392 + t]) * (1.0 - 0.9);
        double cur = 0.0;
        float* eo = env + (size_t)(b * 8 + t) * 128;
        for (int fr = 0; fr < 128; fr++) {
            cur = cur + amp_d[fr] * ha;
            cur = fmin(fmax(cur, 0.0), 1.0);
            eo[fr] = (float)cur;
            cur *= hd;
        }
    }
}

// ---------------------------------------------------------------------------
// Kernel 2: FFT with wave-local planes. 16384 = 16 (cross-wave) x 1024
// (wave-private, radix 4x16x16). 4 workgroup barriers total.
// Twiddles via HW v_sin/v_cos (revolution domain) on exact integer fractions.
// ---------------------------------------------------------------------------
// e^{+2*pi*i*f}, f in [0,1)
__device__ __forceinline__ float2 cwf(float f) {
    return make_float2(__builtin_amdgcn_cosf(f), __builtin_amdgcn_sinf(f));
}
__device__ __forceinline__ float2 mul_e(float2 a, float2 w) {      // a * w
    return make_float2(a.x * w.x - a.y * w.y, a.x * w.y + a.y * w.x);
}
__device__ __forceinline__ float2 mul_econj(float2 a, float2 w) {  // a * conj(w)
    return make_float2(a.x * w.x + a.y * w.y, a.y * w.x - a.x * w.y);
}
__device__ __forceinline__ float2 cmulc(float2 a, float2 b) {
    return make_float2(a.x * b.x - a.y * b.y, a.x * b.y + a.y * b.x);
}

template<int INV>
__device__ __forceinline__ void fft4(float2& x0, float2& x1, float2& x2, float2& x3) {
    float2 s02 = make_float2(x0.x + x2.x, x0.y + x2.y);
    float2 d02 = make_float2(x0.x - x2.x, x0.y - x2.y);
    float2 s13 = make_float2(x1.x + x3.x, x1.y + x3.y);
    float2 d13 = make_float2(x1.x - x3.x, x1.y - x3.y);
    float2 j13 = INV ? make_float2(-d13.y, d13.x) : make_float2(d13.y, -d13.x);
    x0 = make_float2(s02.x + s13.x, s02.y + s13.y);
    x2 = make_float2(s02.x - s13.x, s02.y - s13.y);
    x1 = make_float2(d02.x + j13.x, d02.y + j13.y);
    x3 = make_float2(d02.x - j13.x, d02.y - j13.y);
}

// After fft16, natural-order output index c lives in register V16(v,c).
#define V16(v, c) v[((((c) & 3) << 2) | ((c) >> 2))]

template<int INV>
__device__ __forceinline__ void fft16(float2 v[16]) {
    const float s = INV ? 1.0f : -1.0f;
#pragma unroll
    for (int b = 0; b < 4; b++) fft4<INV>(v[b], v[4 + b], v[8 + b], v[12 + b]);
    v[5]  = cmulc(v[5],  make_float2(0.9238795325f,  s * 0.3826834324f));
    v[9]  = cmulc(v[9],  make_float2(0.7071067812f,  s * 0.7071067812f));
    v[13] = cmulc(v[13], make_float2(0.3826834324f,  s * 0.9238795325f));
    v[6]  = cmulc(v[6],  make_float2(0.7071067812f,  s * 0.7071067812f));
    v[10] = cmulc(v[10], make_float2(0.0f,           s * 1.0f));
    v[14] = cmulc(v[14], make_float2(-0.7071067812f, s * 0.7071067812f));
    v[7]  = cmulc(v[7],  make_float2(0.3826834324f,  s * 0.9238795325f));
    v[11] = cmulc(v[11], make_float2(-0.7071067812f, s * 0.7071067812f));
    v[15] = cmulc(v[15], make_float2(-0.9238795325f, s * -0.3826834324f));
#pragma unroll
    for (int p = 0; p < 4; p++) fft4<INV>(v[4 * p], v[4 * p + 1], v[4 * p + 2], v[4 * p + 3]);
}

// spectral k (0..16383) -> LDS index. plane = k&15; within-plane spectral k2=k>>4
// stored at slot s = 256*(k2&3) + 16*((k2>>2)&15) + (k2>>6), pitched.
__device__ __forceinline__ int zaddr(int k) {
    int p = k & 15, k2 = k >> 4;
    int s = 256 * (k2 & 3) + 16 * ((k2 >> 2) & 15) + (k2 >> 6);
    return p * PSTRIDE + s + (s >> 4);
}

// forward wave-local 1024-pt FFT on plane (lane l). Input natural n2.
// Output: digit (k4,kb,kc) at pitched slot 272*k4 + 17*kb + kc.
__device__ __forceinline__ void plane_fwd(float2* __restrict__ Zp, int l) {
    // A: radix-4 over stride 256, natural, thread-private per j-group
#pragma unroll
    for (int j = 0; j < 4; j++) {
        const int r = 64 * j + l;
        float2 u0 = Zp[r], u1 = Zp[256 + r], u2 = Zp[512 + r], u3 = Zp[768 + r];
        fft4<0>(u0, u1, u2, u3);
        Zp[r] = u0;
        Zp[256 + r] = mul_econj(u1, cwf((float)r       * (1.f / 1024.f)));
        Zp[512 + r] = mul_econj(u2, cwf((float)(2 * r) * (1.f / 1024.f)));
        Zp[768 + r] = mul_econj(u3, cwf((float)(3 * r) * (1.f / 1024.f)));
    }
    // B: fft16 over stride 16 (natural read), write pitched
    {
        const int k4 = l >> 4, c = l & 15;
        const int nbase = 256 * k4 + c;
        float2 v[16];
#pragma unroll
        for (int b = 0; b < 16; b++) v[b] = Zp[nbase + 16 * b];
        fft16<0>(v);
        const int pbase = 272 * k4 + c;
        Zp[pbase] = V16(v, 0);
#pragma unroll
        for (int kb = 1; kb < 16; kb++)
            Zp[pbase + 17 * kb] = mul_econj(V16(v, kb), cwf((float)(c * kb) * (1.f / 256.f)));
    }
    // C: fft16 over stride 1 (pitched blocks), in place
    {
        const int pbase = 272 * (l >> 4) + 17 * (l & 15);
        float2 v[16];
#pragma unroll
        for (int c = 0; c < 16; c++) v[c] = Zp[pbase + c];
        fft16<0>(v);
#pragma unroll
        for (int kc = 0; kc < 16; kc++) Zp[pbase + kc] = V16(v, kc);
    }
}

// inverse wave-local 1024-pt FFT (mirror order, conjugate twiddles), all pitched.
__device__ __forceinline__ void plane_inv(float2* __restrict__ Zp, int l) {
    // C-inv: fft16 over kc (stride 1, pitched); then undo T2: W_256^{+nc*kb}
    {
        const int kb = l & 15;
        const int pbase = 272 * (l >> 4) + 17 * kb;
        float2 v[16];
#pragma unroll
        for (int kc = 0; kc < 16; kc++) v[kc] = Zp[pbase + kc];
        fft16<1>(v);
        Zp[pbase] = V16(v, 0);
#pragma unroll
        for (int nc = 1; nc < 16; nc++)
            Zp[pbase + nc] = mul_e(V16(v, nc), cwf((float)(kb * nc) * (1.f / 256.f)));
    }
    // B-inv: fft16 over kb (stride 17, pitched); then undo T1: W_1024^{+(16nb+nc)*k4}
    {
        const int k4 = l >> 4, nc = l & 15;
        const int pbase = 272 * k4 + nc;
        float2 v[16];
#pragma unroll
        for (int kb = 0; kb < 16; kb++) v[kb] = Zp[pbase + 17 * kb];
        fft16<1>(v);
#pragma unroll
        for (int nb = 0; nb < 16; nb++) {
            float2 val = V16(v, nb);
            if (k4 != 0)
                val = mul_e(val, cwf((float)((16 * nb + nc) * k4) * (1.f / 1024.f)));
            Zp[pbase + 17 * nb] = val;
        }
    }
    // A-inv: fft4 over k4 (stride 272, pitched), thread-private per j-group
#pragma unroll
    for (int j = 0; j < 4; j++) {
        const int r = 64 * j + l;
        const int rp = r + (r >> 4);
        float2 u0 = Zp[rp], u1 = Zp[272 + rp], u2 = Zp[544 + rp], u3 = Zp[816 + rp];
        fft4<1>(u0, u1, u2, u3);
        Zp[rp] = u0; Zp[272 + rp] = u1; Zp[544 + rp] = u2; Zp[816 + rp] = u3;
    }
}

__device__ __forceinline__ float hinterp64(const float* f, int j) {
    float pos = ((float)j + 0.5f) * (1.0f / 256.0f) - 0.5f;
    pos = fminf(fmaxf(pos, 0.0f), 63.0f);
    int lo = (int)pos;
    int hi = min(lo + 1, 63);
    float w = pos - (float)lo;
    return f[lo] * (1.0f - w) + f[hi] * w;
}

__global__ __launch_bounds__(1024, 4) void fft_kernel(
    const float* __restrict__ noise, const float* __restrict__ amp,
    const float* __restrict__ fenv, float* __restrict__ filt)
{
    __shared__ float2 Z[16 * PSTRIDE];   // 139,392 B
    __shared__ float fenv_s[64];
    __shared__ float amp_s[128];
    const int bb = blockIdx.x;
    const int tid = threadIdx.x;
    const int wv = tid >> 6, l = tid & 63;

    if (tid < 64) fenv_s[tid] = fenv[bb * 64 + tid];
    if (tid < 128) amp_s[tid] = amp[bb * 128 + tid];

    const float2* nz = (const float2*)(noise + (size_t)bb * NSAMP);

    // ---- forward outer: in-thread fft16 over n1 (stride 1024), scatter to planes
    {
        float2 v[16];
#pragma unroll
        for (int a = 0; a < 16; a++) {
            float2 t = nz[a * 1024 + tid];
            v[a] = make_float2(t.x * 2.f - 1.f, t.y * 2.f - 1.f);
        }
        fft16<0>(v);
        Z[tid] = V16(v, 0);
#pragma unroll
        for (int k1 = 1; k1 < 16; k1++)
            Z[k1 * PSTRIDE + tid] =
                mul_econj(V16(v, k1), cwf((float)(tid * k1) * (1.f / 16384.f)));
    }
    __syncthreads();

    plane_fwd(Z + wv * PSTRIDE, l);     // wave-local, no barriers
    __syncthreads();

    // ---- spectral combine: unpack rfft bins, multiply by H, repack, fold 1/M
    const float invM = 1.0f / (float)MHALF;
    for (int k = tid; k <= 8192; k += 1024) {
        if (k == 0) {
            int i0 = zaddr(0);
            float2 Z0 = Z[i0];
            float Y0 = (Z0.x + Z0.y) * hinterp64(fenv_s, 0);
            float vv = Y0 * 0.5f * invM;
            Z[i0] = make_float2(vv, vv);
        } else if (k == 8192) {
            int i8 = zaddr(8192);
            float s = hinterp64(fenv_s, 8192) * invM;
            float2 Zk = Z[i8];
            Z[i8] = make_float2(Zk.x * s, Zk.y * s);
        } else {
            int ik = zaddr(k), imk = zaddr(16384 - k);
            float2 Zk = Z[ik], Zm = Z[imk];
            float Ex = 0.5f * (Zk.x + Zm.x);
            float Ey = 0.5f * (Zk.y - Zm.y);
            float Ox = 0.5f * (Zk.y + Zm.y);
            float Oy = -0.5f * (Zk.x - Zm.x);
            float f = (float)k * (1.0f / 32768.0f);   // <= 0.25 rev
            float sn = __builtin_amdgcn_sinf(f);
            float cs = __builtin_amdgcn_cosf(f);
            float Xkx = Ex + cs * Ox + sn * Oy;
            float Xky = Ey + cs * Oy - sn * Ox;
            float Xmx = Ex - cs * Ox - sn * Oy;
            float Xmy = -Ey + cs * Oy - sn * Ox;
            float Hk = hinterp64(fenv_s, k);
            float Hm = hinterp64(fenv_s, 16384 - k);
            float Ykx = Xkx * Hk, Yky = Xky * Hk;
            float Ymx = Xmx * Hm, Ymy = Xmy * Hm;
            float Er = 0.5f * (Ykx + Ymx);
            float Ei = 0.5f * (Yky - Ymy);
            float Pr = 0.5f * (Ykx - Ymx);
            float Pi = 0.5f * (Yky + Ymy);
            float Oyx = Pr * cs - Pi * sn;
            float Oyy = Pr * sn + Pi * cs;
            Z[ik]  = make_float2((Er - Oyy) * invM, (Ei + Oyx) * invM);
            Z[imk] = make_float2((Er + Oyy) * invM, (-Ei + Oyx) * invM);
        }
    }
    __syncthreads();

    plane_inv(Z + wv * PSTRIDE, l);     // wave-local, no barriers
    __syncthreads();

    // ---- inverse outer: gather across planes, twiddle, fft16, amp, store
    {
        const int tp = tid + (tid >> 4);
        float2 v[16];
#pragma unroll
        for (int k1 = 0; k1 < 16; k1++) v[k1] = Z[k1 * PSTRIDE + tp];
#pragma unroll
        for (int k1 = 1; k1 < 16; k1++)
            v[k1] = mul_e(v[k1], cwf((float)(tid * k1) * (1.f / 16384.f)));
        fft16<1>(v);

        float2* fo = (float2*)(filt + (size_t)bb * NSAMP);
#pragma unroll
        for (int m = 0; m < 16; m++) {
            float2 y = V16(v, m);
            int A = m * 1024 + tid;
            int s0 = 2 * A;
            float p0 = ((float)s0 + 0.5f) * (1.0f / 256.0f) - 0.5f;
            float p1 = p0 + (1.0f / 256.0f);
            p0 = fminf(fmaxf(p0, 0.0f), 127.0f);
            p1 = fminf(fmaxf(p1, 0.0f), 127.0f);
            int l0 = (int)p0, l1 = (int)p1;
            int h0 = min(l0 + 1, 127), h1 = min(l1 + 1, 127);
            float w0a = p0 - (float)l0, w1a = p1 - (float)l1;
            float a0 = amp_s[l0] * (1.0f - w0a) + amp_s[h0] * w0a;
            float a1 = amp_s[l1] * (1.0f - w1a) + amp_s[h1] * w1a;
            a0 = fminf(fmaxf(a0, 0.0f), 1.0f);
            a1 = fminf(fmaxf(a1, 0.0f), 1.0f);
            fo[A] = make_float2(y.x * a0, y.y * a1);
        }
    }
}

// ---------------------------------------------------------------------------
// Kernel 3: final synthesis — integer Q0.64 phase + hw v_sin (revolutions).
// ---------------------------------------------------------------------------
__global__ __launch_bounds__(256) void synth_kernel(
    const unsigned long long* __restrict__ step, const float* __restrict__ env,
    const float* __restrict__ filt, float* __restrict__ out)
{
    const int chunk = blockIdx.x;   // 0..31
    const int g = blockIdx.y;       // 0..31
    const int tid = threadIdx.x;
    __shared__ float env_s[64 * 128];
    __shared__ unsigned long long step_s[64];

    const float* eg = env + (size_t)g * 64 * 128;
    for (int i = tid; i < 64 * 128; i += 256) env_s[i] = eg[i];
    if (tid < 64) step_s[tid] = step[g * 64 + tid];
    __syncthreads();

    const int s0 = chunk * 1024 + tid * 4;

    float4 aF = make_float4(0.f, 0.f, 0.f, 0.f);
#pragma unroll
    for (int e = 0; e < 8; e++) {
        const float4 f = *(const float4*)(filt + ((size_t)(g * 8 + e)) * NSAMP + s0);
        aF.x += f.x; aF.y += f.y; aF.z += f.z; aF.w += f.w;
    }

    float c0v[4], c1v[4], c2v[4];
    int lo0;
    {
        float pos0 = ((float)s0 + 0.5f) * (1.0f / 256.0f) - 0.5f;
        pos0 = fminf(fmaxf(pos0, 0.0f), 127.0f);
        lo0 = (int)pos0;
#pragma unroll
        for (int k = 0; k < 4; k++) {
            float pos = ((float)(s0 + k) + 0.5f) * (1.0f / 256.0f) - 0.5f;
            pos = fminf(fmaxf(pos, 0.0f), 127.0f);
            int lo = (int)pos;
            float w = pos - (float)lo;
            if (lo == lo0) { c0v[k] = 1.0f - w; c1v[k] = w;        c2v[k] = 0.0f; }
            else           { c0v[k] = 0.0f;     c1v[k] = 1.0f - w; c2v[k] = w;    }
        }
    }
    const int i1 = min(lo0 + 1, 127);
    int lo3b = lo0;
    {
        float pos = ((float)(s0 + 3) + 0.5f) * (1.0f / 256.0f) - 0.5f;
        pos = fminf(fmaxf(pos, 0.0f), 127.0f);
        lo3b = (int)pos;
    }
    const int i2 = min(lo3b + 1, 127);

    float a0 = 0.f, a1 = 0.f, a2 = 0.f, a3 = 0.f;
    const unsigned long long n0 = (unsigned long long)(unsigned)(s0 + 1);

#pragma unroll 8
    for (int idx = 0; idx < 64; idx++) {
        const unsigned long long st = step_s[idx];
        unsigned long long p = st * n0;
        const float* er = env_s + (idx << 7);
        const float v0 = er[lo0], v1 = er[i1], v2 = er[i2];

        float ev, fr, sn;

        fr = (float)(unsigned)(p >> 32) * 0x1p-32f;
        sn = __builtin_amdgcn_sinf(fr);
        ev = fmaf(v0, c0v[0], fmaf(v1, c1v[0], v2 * c2v[0]));
        a0 = fmaf(ev, sn, a0); p += st;

        fr = (float)(unsigned)(p >> 32) * 0x1p-32f;
        sn = __builtin_amdgcn_sinf(fr);
        ev = fmaf(v0, c0v[1], fmaf(v1, c1v[1], v2 * c2v[1]));
        a1 = fmaf(ev, sn, a1); p += st;

        fr = (float)(unsigned)(p >> 32) * 0x1p-32f;
        sn = __builtin_amdgcn_sinf(fr);
        ev = fmaf(v0, c0v[2], fmaf(v1, c1v[2], v2 * c2v[2]));
        a2 = fmaf(ev, sn, a2); p += st;

        fr = (float)(unsigned)(p >> 32) * 0x1p-32f;
        sn = __builtin_amdgcn_sinf(fr);
        ev = fmaf(v0, c0v[3], fmaf(v1, c1v[3], v2 * c2v[3]));
        a3 = fmaf(ev, sn, a3);
    }

    float4 r;
    r.x = a0 + 8.0f * aF.x;
    r.y = a1 + 8.0f * aF.y;
    r.z = a2 + 8.0f * aF.z;
    r.w = a3 + 8.0f * aF.w;
    *(float4*)(out + (size_t)g * NSAMP + s0) = r;
}

extern "C" void kernel_launch(void* const* d_in, const int* in_sizes, int n_in,
                              void* d_out, int out_size, void* d_ws, size_t ws_size,
                              hipStream_t stream)
{
    (void)in_sizes; (void)n_in; (void)out_size; (void)ws_size;
    const float* packed = (const float*)d_in[0];
    const float* freqs  = (const float*)d_in[1];
    const float* noise  = (const float*)d_in[2];
    float* out = (float*)d_out;
    char* ws = (char*)d_ws;

    unsigned long long* step = (unsigned long long*)(ws);
    float* env  = (float*)(ws + 16384);
    float* amp  = (float*)(ws + 16384 + 1048576);
    float* fenv = (float*)(ws + 16384 + 1048576 + 131072);
    float* filt = (float*)(ws + 16384 + 1048576 + 131072 + 65536);

    hipLaunchKernelGGL(prep_kernel, dim3(256), dim3(128), 0, stream,
                       packed, freqs, step, env, amp, fenv);
    hipLaunchKernelGGL(fft_kernel, dim3(256), dim3(1024), 0, stream,
                       noise, amp, fenv, filt);
    hipLaunchKernelGGL(synth_kernel, dim3(32, 32), dim3(256), 0, stream,
                       step, env, filt, out);
}

// Round 7
// 144.120 us; speedup vs baseline: 1.1362x; 1.1362x over previous
//
#include <hip/hip_runtime.h>
#include <math.h>

#ifndef M_PI
#define M_PI 3.14159265358979323846
#endif

#define NSAMP 32768
#define MHALF 16384
#define TWO_PI_F 6.2831853071795864f
#define PSTRIDE 1089   // plane stride in float2; 1089&15==1 spreads planes across bank pairs

__device__ __forceinline__ double dsig(double x) { return 1.0 / (1.0 + exp(-x)); }

// ---------------------------------------------------------------------------
// Kernel 1: per-batch parameter decode (fp64 to match the np/f64 reference).
// Emits per-oscillator phase step as Q0.64 fixed point (u64).
// ---------------------------------------------------------------------------
__global__ __launch_bounds__(128) void prep_kernel(
    const float* __restrict__ packed, const float* __restrict__ freqs,
    unsigned long long* __restrict__ step, float* __restrict__ env,
    float* __restrict__ amp, float* __restrict__ fenv)
{
    int b = blockIdx.x;
    int t = threadIdx.x;  // 0..127
    const float* pk = packed + b * 464;
    __shared__ double sh_num[128];
    __shared__ double sh_den[128];
    __shared__ double amp_d[128];

    double e_t = exp(dsig((double)pk[t]));
    sh_den[t] = e_t;
    sh_num[t] = e_t * (double)freqs[t];

    double av = dsig((double)pk[256 + t]) * 2.0 - 1.0;
    amp_d[t] = av;
    amp[b * 128 + t] = (float)av;

    if (t < 64) fenv[b * 64 + t] = (float)dsig((double)pk[400 + t]);
    __syncthreads();

    for (int off = 64; off > 0; off >>= 1) {
        if (t < off) { sh_den[t] += sh_den[t + off]; sh_num[t] += sh_num[t + off]; }
        __syncthreads();
    }

    if (t < 8) {
        const double NYQ = 11025.0;
        const double MIN_F0 = 40.0 / NYQ;
        const double MAX_F0 = 3000.0 / NYQ;
        const double F0_SPAN = MAX_F0 - MIN_F0;
        double f0 = sh_num[0] / sh_den[0];
        double F = f0 * NYQ;
        double G = MIN_F0 + F * F0_SPAN;
        double oscf = G * (double)(t + 1);
        double r = oscf / NYQ * M_PI;          // radians / sample
        double rv = r / (2.0 * M_PI);          // revolutions / sample
        rv -= floor(rv);
        step[b * 8 + t] = (unsigned long long)(rv * 18446744073709551616.0);

        double ha = dsig((double)pk[384 + t]);
        double hd = 0.9 + dsig((double)pk[392 + t]) * (1.0 - 0.9);
        double cur = 0.0;
        float* eo = env + (size_t)(b * 8 + t) * 128;
        for (int fr = 0; fr < 128; fr++) {
            cur = cur + amp_d[fr] * ha;
            cur = fmin(fmax(cur, 0.0), 1.0);
            eo[fr] = (float)cur;
            cur *= hd;
        }
    }
}

// ---------------------------------------------------------------------------
// Kernel 2: FFT with wave-local planes. 16384 = 16 (cross-wave) x 1024
// (wave-private, radix 4x16x16). 4 workgroup barriers total.
// Twiddles: ONE __sincosf per loop + geometric recurrence (w_k = w_{k-1}*w).
// The serial chain is un-hoistable -> no register blow-up (R6 lesson).
// ---------------------------------------------------------------------------
__device__ __forceinline__ float2 cmul(float2 a, float2 b) {
    return make_float2(a.x * b.x - a.y * b.y, a.x * b.y + a.y * b.x);
}

template<int INV>
__device__ __forceinline__ void fft4(float2& x0, float2& x1, float2& x2, float2& x3) {
    float2 s02 = make_float2(x0.x + x2.x, x0.y + x2.y);
    float2 d02 = make_float2(x0.x - x2.x, x0.y - x2.y);
    float2 s13 = make_float2(x1.x + x3.x, x1.y + x3.y);
    float2 d13 = make_float2(x1.x - x3.x, x1.y - x3.y);
    float2 j13 = INV ? make_float2(-d13.y, d13.x) : make_float2(d13.y, -d13.x);
    x0 = make_float2(s02.x + s13.x, s02.y + s13.y);
    x2 = make_float2(s02.x - s13.x, s02.y - s13.y);
    x1 = make_float2(d02.x + j13.x, d02.y + j13.y);
    x3 = make_float2(d02.x - j13.x, d02.y - j13.y);
}

// After fft16, natural-order output index c lives in register V16(v,c).
#define V16(v, c) v[((((c) & 3) << 2) | ((c) >> 2))]

template<int INV>
__device__ __forceinline__ void fft16(float2 v[16]) {
    const float s = INV ? 1.0f : -1.0f;
#pragma unroll
    for (int b = 0; b < 4; b++) fft4<INV>(v[b], v[4 + b], v[8 + b], v[12 + b]);
    v[5]  = cmul(v[5],  make_float2(0.9238795325f,  s * 0.3826834324f));
    v[9]  = cmul(v[9],  make_float2(0.7071067812f,  s * 0.7071067812f));
    v[13] = cmul(v[13], make_float2(0.3826834324f,  s * 0.9238795325f));
    v[6]  = cmul(v[6],  make_float2(0.7071067812f,  s * 0.7071067812f));
    v[10] = cmul(v[10], make_float2(0.0f,           s * 1.0f));
    v[14] = cmul(v[14], make_float2(-0.7071067812f, s * 0.7071067812f));
    v[7]  = cmul(v[7],  make_float2(0.3826834324f,  s * 0.9238795325f));
    v[11] = cmul(v[11], make_float2(-0.7071067812f, s * 0.7071067812f));
    v[15] = cmul(v[15], make_float2(-0.9238795325f, s * -0.3826834324f));
#pragma unroll
    for (int p = 0; p < 4; p++) fft4<INV>(v[4 * p], v[4 * p + 1], v[4 * p + 2], v[4 * p + 3]);
}

// spectral k (0..16383) -> LDS index. plane = k&15; within-plane spectral k2=k>>4
// stored at slot s = 256*(k2&3) + 16*((k2>>2)&15) + (k2>>6), pitched.
__device__ __forceinline__ int zaddr(int k) {
    int p = k & 15, k2 = k >> 4;
    int s = 256 * (k2 & 3) + 16 * ((k2 >> 2) & 15) + (k2 >> 6);
    return p * PSTRIDE + s + (s >> 4);
}

// forward wave-local 1024-pt FFT on plane (lane l). Input natural n2.
// Output: digit (k4,kb,kc) at pitched slot 272*k4 + 17*kb + kc.
__device__ __forceinline__ void plane_fwd(float2* __restrict__ Zp, int l) {
    // A: radix-4 over stride 256; twiddle base w1 = e^{-2pi i r/1024}, r = 64j+l
    {
        float sn, cs;
        __sincosf(TWO_PI_F * (float)l * (1.f / 1024.f), &sn, &cs);
        float2 w1 = make_float2(cs, -sn);
        const float2 jstep = make_float2(0.9238795325f, -0.3826834324f); // e^{-2pi i/16}
#pragma unroll
        for (int j = 0; j < 4; j++) {
            const int r = 64 * j + l;
            float2 u0 = Zp[r], u1 = Zp[256 + r], u2 = Zp[512 + r], u3 = Zp[768 + r];
            fft4<0>(u0, u1, u2, u3);
            float2 w2 = cmul(w1, w1);
            float2 w3 = cmul(w2, w1);
            Zp[r] = u0;
            Zp[256 + r] = cmul(u1, w1);
            Zp[512 + r] = cmul(u2, w2);
            Zp[768 + r] = cmul(u3, w3);
            w1 = cmul(w1, jstep);
        }
    }
    // B: fft16 over stride 16 (natural read), write pitched; tw = e^{-2pi i c kb/256}
    {
        const int k4 = l >> 4, c = l & 15;
        const int nbase = 256 * k4 + c;
        float sn, cs;
        __sincosf(TWO_PI_F * (float)c * (1.f / 256.f), &sn, &cs);
        const float2 wc = make_float2(cs, -sn);
        float2 v[16];
#pragma unroll
        for (int b = 0; b < 16; b++) v[b] = Zp[nbase + 16 * b];
        fft16<0>(v);
        const int pbase = 272 * k4 + c;
        Zp[pbase] = V16(v, 0);
        float2 w = wc;
#pragma unroll
        for (int kb = 1; kb < 16; kb++) {
            Zp[pbase + 17 * kb] = cmul(V16(v, kb), w);
            w = cmul(w, wc);
        }
    }
    // C: fft16 over stride 1 (pitched blocks), in place
    {
        const int pbase = 272 * (l >> 4) + 17 * (l & 15);
        float2 v[16];
#pragma unroll
        for (int c = 0; c < 16; c++) v[c] = Zp[pbase + c];
        fft16<0>(v);
#pragma unroll
        for (int kc = 0; kc < 16; kc++) Zp[pbase + kc] = V16(v, kc);
    }
}

// inverse wave-local 1024-pt FFT (mirror order, conjugate twiddles), all pitched.
__device__ __forceinline__ void plane_inv(float2* __restrict__ Zp, int l) {
    // C-inv: fft16 over kc (stride 1, pitched); then undo T2: e^{+2pi i kb nc/256}
    {
        const int kb = l & 15;
        const int pbase = 272 * (l >> 4) + 17 * kb;
        float sn, cs;
        __sincosf(TWO_PI_F * (float)kb * (1.f / 256.f), &sn, &cs);
        const float2 wkb = make_float2(cs, sn);
        float2 v[16];
#pragma unroll
        for (int kc = 0; kc < 16; kc++) v[kc] = Zp[pbase + kc];
        fft16<1>(v);
        Zp[pbase] = V16(v, 0);
        float2 w = wkb;
#pragma unroll
        for (int nc = 1; nc < 16; nc++) {
            Zp[pbase + nc] = cmul(V16(v, nc), w);
            w = cmul(w, wkb);
        }
    }
    // B-inv: fft16 over kb (stride 17); then undo T1: e^{+2pi i (16nb+nc) k4/1024}
    {
        const int k4 = l >> 4, nc = l & 15;
        const int pbase = 272 * k4 + nc;
        float sni, csi;
        __sincosf(TWO_PI_F * (float)(nc * k4) * (1.f / 1024.f), &sni, &csi);
        float2 t = make_float2(csi, sni);
        float sns, css;
        __sincosf(TWO_PI_F * (float)k4 * (1.f / 64.f), &sns, &css);
        const float2 st = make_float2(css, sns);
        float2 v[16];
#pragma unroll
        for (int kb = 0; kb < 16; kb++) v[kb] = Zp[pbase + 17 * kb];
        fft16<1>(v);
#pragma unroll
        for (int nb = 0; nb < 16; nb++) {
            Zp[pbase + 17 * nb] = cmul(V16(v, nb), t);
            t = cmul(t, st);
        }
    }
    // A-inv: fft4 over k4 (stride 272, pitched), thread-private per j-group
#pragma unroll
    for (int j = 0; j < 4; j++) {
        const int r = 64 * j + l;
        const int rp = r + (r >> 4);
        float2 u0 = Zp[rp], u1 = Zp[272 + rp], u2 = Zp[544 + rp], u3 = Zp[816 + rp];
        fft4<1>(u0, u1, u2, u3);
        Zp[rp] = u0; Zp[272 + rp] = u1; Zp[544 + rp] = u2; Zp[816 + rp] = u3;
    }
}

__device__ __forceinline__ float hinterp64(const float* f, int j) {
    float pos = ((float)j + 0.5f) * (1.0f / 256.0f) - 0.5f;
    pos = fminf(fmaxf(pos, 0.0f), 63.0f);
    int lo = (int)pos;
    int hi = min(lo + 1, 63);
    float w = pos - (float)lo;
    return f[lo] * (1.0f - w) + f[hi] * w;
}

__global__ __launch_bounds__(1024, 4) void fft_kernel(
    const float* __restrict__ noise, const float* __restrict__ amp,
    const float* __restrict__ fenv, float* __restrict__ filt)
{
    __shared__ float2 Z[16 * PSTRIDE];   // 139,392 B
    __shared__ float fenv_s[64];
    __shared__ float amp_s[128];
    const int bb = blockIdx.x;
    const int tid = threadIdx.x;
    const int wv = tid >> 6, l = tid & 63;

    if (tid < 64) fenv_s[tid] = fenv[bb * 64 + tid];
    if (tid < 128) amp_s[tid] = amp[bb * 128 + tid];

    const float2* nz = (const float2*)(noise + (size_t)bb * NSAMP);

    // ---- forward outer: in-thread fft16 over n1 (stride 1024), scatter to planes
    // tw = e^{-2pi i tid k1/16384} via recurrence
    {
        float2 v[16];
#pragma unroll
        for (int a = 0; a < 16; a++) {
            float2 t = nz[a * 1024 + tid];
            v[a] = make_float2(t.x * 2.f - 1.f, t.y * 2.f - 1.f);
        }
        fft16<0>(v);
        float sn, cs;
        __sincosf(TWO_PI_F * (float)tid * (1.f / 16384.f), &sn, &cs);
        const float2 ws = make_float2(cs, -sn);
        Z[tid] = V16(v, 0);
        float2 w = ws;
#pragma unroll
        for (int k1 = 1; k1 < 16; k1++) {
            Z[k1 * PSTRIDE + tid] = cmul(V16(v, k1), w);
            w = cmul(w, ws);
        }
    }
    __syncthreads();

    plane_fwd(Z + wv * PSTRIDE, l);     // wave-local, no barriers
    __syncthreads();

    // ---- spectral combine: unpack rfft bins, multiply by H, repack, fold 1/M
    // tw_k = e^{+i pi k/16384} via recurrence: init at k=tid, step e^{+i pi/16}
    const float invM = 1.0f / (float)MHALF;
    {
        float sn0, cs0;
        __sincosf((float)M_PI * (float)tid * (1.f / 16384.f), &sn0, &cs0);
        float2 t = make_float2(cs0, sn0);
        const float2 tstep = make_float2(0.98078528040323f, 0.19509032201613f); // e^{+i pi/16}
        for (int k = tid; k <= 8192; k += 1024) {
            if (k == 0) {
                int i0 = zaddr(0);
                float2 Z0 = Z[i0];
                float Y0 = (Z0.x + Z0.y) * hinterp64(fenv_s, 0);
                float vv = Y0 * 0.5f * invM;
                Z[i0] = make_float2(vv, vv);
            } else if (k == 8192) {
                int i8 = zaddr(8192);
                float s = hinterp64(fenv_s, 8192) * invM;
                float2 Zk = Z[i8];
                Z[i8] = make_float2(Zk.x * s, Zk.y * s);
            } else {
                int ik = zaddr(k), imk = zaddr(16384 - k);
                float2 Zk = Z[ik], Zm = Z[imk];
                float Ex = 0.5f * (Zk.x + Zm.x);
                float Ey = 0.5f * (Zk.y - Zm.y);
                float Ox = 0.5f * (Zk.y + Zm.y);
                float Oy = -0.5f * (Zk.x - Zm.x);
                float cs = t.x, sn = t.y;
                float Xkx = Ex + cs * Ox + sn * Oy;
                float Xky = Ey + cs * Oy - sn * Ox;
                float Xmx = Ex - cs * Ox - sn * Oy;
                float Xmy = -Ey + cs * Oy - sn * Ox;
                float Hk = hinterp64(fenv_s, k);
                float Hm = hinterp64(fenv_s, 16384 - k);
                float Ykx = Xkx * Hk, Yky = Xky * Hk;
                float Ymx = Xmx * Hm, Ymy = Xmy * Hm;
                float Er = 0.5f * (Ykx + Ymx);
                float Ei = 0.5f * (Yky - Ymy);
                float Pr = 0.5f * (Ykx - Ymx);
                float Pi = 0.5f * (Yky + Ymy);
                float Oyx = Pr * cs - Pi * sn;
                float Oyy = Pr * sn + Pi * cs;
                Z[ik]  = make_float2((Er - Oyy) * invM, (Ei + Oyx) * invM);
                Z[imk] = make_float2((Er + Oyy) * invM, (-Ei + Oyx) * invM);
            }
            t = cmul(t, tstep);
        }
    }
    __syncthreads();

    plane_inv(Z + wv * PSTRIDE, l);     // wave-local, no barriers
    __syncthreads();

    // ---- inverse outer: gather across planes, twiddle (recurrence), fft16, amp, store
    {
        const int tp = tid + (tid >> 4);
        float2 v[16];
#pragma unroll
        for (int k1 = 0; k1 < 16; k1++) v[k1] = Z[k1 * PSTRIDE + tp];
        float sn, cs;
        __sincosf(TWO_PI_F * (float)tid * (1.f / 16384.f), &sn, &cs);
        const float2 wg = make_float2(cs, sn);
        float2 w = wg;
#pragma unroll
        for (int k1 = 1; k1 < 16; k1++) {
            v[k1] = cmul(v[k1], w);
            w = cmul(w, wg);
        }
        fft16<1>(v);

        float2* fo = (float2*)(filt + (size_t)bb * NSAMP);
#pragma unroll
        for (int m = 0; m < 16; m++) {
            float2 y = V16(v, m);
            int A = m * 1024 + tid;
            int s0 = 2 * A;
            float p0 = ((float)s0 + 0.5f) * (1.0f / 256.0f) - 0.5f;
            float p1 = p0 + (1.0f / 256.0f);
            p0 = fminf(fmaxf(p0, 0.0f), 127.0f);
            p1 = fminf(fmaxf(p1, 0.0f), 127.0f);
            int l0 = (int)p0, l1 = (int)p1;
            int h0 = min(l0 + 1, 127), h1 = min(l1 + 1, 127);
            float w0a = p0 - (float)l0, w1a = p1 - (float)l1;
            float a0 = amp_s[l0] * (1.0f - w0a) + amp_s[h0] * w0a;
            float a1 = amp_s[l1] * (1.0f - w1a) + amp_s[h1] * w1a;
            a0 = fminf(fmaxf(a0, 0.0f), 1.0f);
            a1 = fminf(fmaxf(a1, 0.0f), 1.0f);
            fo[A] = make_float2(y.x * a0, y.y * a1);
        }
    }
}

// ---------------------------------------------------------------------------
// Kernel 3: final synthesis — integer Q0.64 phase + hw v_sin (revolutions).
// ---------------------------------------------------------------------------
__global__ __launch_bounds__(256) void synth_kernel(
    const unsigned long long* __restrict__ step, const float* __restrict__ env,
    const float* __restrict__ filt, float* __restrict__ out)
{
    const int chunk = blockIdx.x;   // 0..31
    const int g = blockIdx.y;       // 0..31
    const int tid = threadIdx.x;
    __shared__ float env_s[64 * 128];
    __shared__ unsigned long long step_s[64];

    const float* eg = env + (size_t)g * 64 * 128;
    for (int i = tid; i < 64 * 128; i += 256) env_s[i] = eg[i];
    if (tid < 64) step_s[tid] = step[g * 64 + tid];
    __syncthreads();

    const int s0 = chunk * 1024 + tid * 4;

    float4 aF = make_float4(0.f, 0.f, 0.f, 0.f);
#pragma unroll
    for (int e = 0; e < 8; e++) {
        const float4 f = *(const float4*)(filt + ((size_t)(g * 8 + e)) * NSAMP + s0);
        aF.x += f.x; aF.y += f.y; aF.z += f.z; aF.w += f.w;
    }

    float c0v[4], c1v[4], c2v[4];
    int lo0;
    {
        float pos0 = ((float)s0 + 0.5f) * (1.0f / 256.0f) - 0.5f;
        pos0 = fminf(fmaxf(pos0, 0.0f), 127.0f);
        lo0 = (int)pos0;
#pragma unroll
        for (int k = 0; k < 4; k++) {
            float pos = ((float)(s0 + k) + 0.5f) * (1.0f / 256.0f) - 0.5f;
            pos = fminf(fmaxf(pos, 0.0f), 127.0f);
            int lo = (int)pos;
            float w = pos - (float)lo;
            if (lo == lo0) { c0v[k] = 1.0f - w; c1v[k] = w;        c2v[k] = 0.0f; }
            else           { c0v[k] = 0.0f;     c1v[k] = 1.0f - w; c2v[k] = w;    }
        }
    }
    const int i1 = min(lo0 + 1, 127);
    int lo3b = lo0;
    {
        float pos = ((float)(s0 + 3) + 0.5f) * (1.0f / 256.0f) - 0.5f;
        pos = fminf(fmaxf(pos, 0.0f), 127.0f);
        lo3b = (int)pos;
    }
    const int i2 = min(lo3b + 1, 127);

    float a0 = 0.f, a1 = 0.f, a2 = 0.f, a3 = 0.f;
    const unsigned long long n0 = (unsigned long long)(unsigned)(s0 + 1);

#pragma unroll 8
    for (int idx = 0; idx < 64; idx++) {
        const unsigned long long st = step_s[idx];
        unsigned long long p = st * n0;
        const float* er = env_s + (idx << 7);
        const float v0 = er[lo0], v1 = er[i1], v2 = er[i2];

        float ev, fr, sn;

        fr = (float)(unsigned)(p >> 32) * 0x1p-32f;
        sn = __builtin_amdgcn_sinf(fr);
        ev = fmaf(v0, c0v[0], fmaf(v1, c1v[0], v2 * c2v[0]));
        a0 = fmaf(ev, sn, a0); p += st;

        fr = (float)(unsigned)(p >> 32) * 0x1p-32f;
        sn = __builtin_amdgcn_sinf(fr);
        ev = fmaf(v0, c0v[1], fmaf(v1, c1v[1], v2 * c2v[1]));
        a1 = fmaf(ev, sn, a1); p += st;

        fr = (float)(unsigned)(p >> 32) * 0x1p-32f;
        sn = __builtin_amdgcn_sinf(fr);
        ev = fmaf(v0, c0v[2], fmaf(v1, c1v[2], v2 * c2v[2]));
        a2 = fmaf(ev, sn, a2); p += st;

        fr = (float)(unsigned)(p >> 32) * 0x1p-32f;
        sn = __builtin_amdgcn_sinf(fr);
        ev = fmaf(v0, c0v[3], fmaf(v1, c1v[3], v2 * c2v[3]));
        a3 = fmaf(ev, sn, a3);
    }

    float4 r;
    r.x = a0 + 8.0f * aF.x;
    r.y = a1 + 8.0f * aF.y;
    r.z = a2 + 8.0f * aF.z;
    r.w = a3 + 8.0f * aF.w;
    *(float4*)(out + (size_t)g * NSAMP + s0) = r;
}

extern "C" void kernel_launch(void* const* d_in, const int* in_sizes, int n_in,
                              void* d_out, int out_size, void* d_ws, size_t ws_size,
                              hipStream_t stream)
{
    (void)in_sizes; (void)n_in; (void)out_size; (void)ws_size;
    const float* packed = (const float*)d_in[0];
    const float* freqs  = (const float*)d_in[1];
    const float* noise  = (const float*)d_in[2];
    float* out = (float*)d_out;
    char* ws = (char*)d_ws;

    unsigned long long* step = (unsigned long long*)(ws);
    float* env  = (float*)(ws + 16384);
    float* amp  = (float*)(ws + 16384 + 1048576);
    float* fenv = (float*)(ws + 16384 + 1048576 + 131072);
    float* filt = (float*)(ws + 16384 + 1048576 + 131072 + 65536);

    hipLaunchKernelGGL(prep_kernel, dim3(256), dim3(128), 0, stream,
                       packed, freqs, step, env, amp, fenv);
    hipLaunchKernelGGL(fft_kernel, dim3(256), dim3(1024), 0, stream,
                       noise, amp, fenv, filt);
    hipLaunchKernelGGL(synth_kernel, dim3(32, 32), dim3(256), 0, stream,
                       step, env, filt, out);
}

// Round 8
// 134.552 us; speedup vs baseline: 1.2170x; 1.0711x over previous
//
#include <hip/hip_runtime.h>
#include <math.h>

#ifndef M_PI
#define M_PI 3.14159265358979323846
#endif

#define NSAMP 32768
#define MHALF 16384
#define TWO_PI_F 6.2831853071795864f
#define PSTRIDE 1089   // plane stride in float2; 1089&15==1 spreads planes across bank pairs

__device__ __forceinline__ double dsig(double x) { return 1.0 / (1.0 + exp(-x)); }

// ---------------------------------------------------------------------------
// FFT helpers (R7 structure: wave-local planes, recurrence twiddles)
// ---------------------------------------------------------------------------
__device__ __forceinline__ float2 cmul(float2 a, float2 b) {
    return make_float2(a.x * b.x - a.y * b.y, a.x * b.y + a.y * b.x);
}

template<int INV>
__device__ __forceinline__ void fft4(float2& x0, float2& x1, float2& x2, float2& x3) {
    float2 s02 = make_float2(x0.x + x2.x, x0.y + x2.y);
    float2 d02 = make_float2(x0.x - x2.x, x0.y - x2.y);
    float2 s13 = make_float2(x1.x + x3.x, x1.y + x3.y);
    float2 d13 = make_float2(x1.x - x3.x, x1.y - x3.y);
    float2 j13 = INV ? make_float2(-d13.y, d13.x) : make_float2(d13.y, -d13.x);
    x0 = make_float2(s02.x + s13.x, s02.y + s13.y);
    x2 = make_float2(s02.x - s13.x, s02.y - s13.y);
    x1 = make_float2(d02.x + j13.x, d02.y + j13.y);
    x3 = make_float2(d02.x - j13.x, d02.y - j13.y);
}

// After fft16, natural-order output index c lives in register V16(v,c).
#define V16(v, c) v[((((c) & 3) << 2) | ((c) >> 2))]

template<int INV>
__device__ __forceinline__ void fft16(float2 v[16]) {
    const float s = INV ? 1.0f : -1.0f;
#pragma unroll
    for (int b = 0; b < 4; b++) fft4<INV>(v[b], v[4 + b], v[8 + b], v[12 + b]);
    v[5]  = cmul(v[5],  make_float2(0.9238795325f,  s * 0.3826834324f));
    v[9]  = cmul(v[9],  make_float2(0.7071067812f,  s * 0.7071067812f));
    v[13] = cmul(v[13], make_float2(0.3826834324f,  s * 0.9238795325f));
    v[6]  = cmul(v[6],  make_float2(0.7071067812f,  s * 0.7071067812f));
    v[10] = cmul(v[10], make_float2(0.0f,           s * 1.0f));
    v[14] = cmul(v[14], make_float2(-0.7071067812f, s * 0.7071067812f));
    v[7]  = cmul(v[7],  make_float2(0.3826834324f,  s * 0.9238795325f));
    v[11] = cmul(v[11], make_float2(-0.7071067812f, s * 0.7071067812f));
    v[15] = cmul(v[15], make_float2(-0.9238795325f, s * -0.3826834324f));
#pragma unroll
    for (int p = 0; p < 4; p++) fft4<INV>(v[4 * p], v[4 * p + 1], v[4 * p + 2], v[4 * p + 3]);
}

// spectral k (0..16383) -> LDS index.
__device__ __forceinline__ int zaddr(int k) {
    int p = k & 15, k2 = k >> 4;
    int s = 256 * (k2 & 3) + 16 * ((k2 >> 2) & 15) + (k2 >> 6);
    return p * PSTRIDE + s + (s >> 4);
}

// forward wave-local 1024-pt FFT on plane (lane l).
__device__ __forceinline__ void plane_fwd(float2* __restrict__ Zp, int l) {
    {
        float sn, cs;
        __sincosf(TWO_PI_F * (float)l * (1.f / 1024.f), &sn, &cs);
        float2 w1 = make_float2(cs, -sn);
        const float2 jstep = make_float2(0.9238795325f, -0.3826834324f); // e^{-2pi i/16}
#pragma unroll
        for (int j = 0; j < 4; j++) {
            const int r = 64 * j + l;
            float2 u0 = Zp[r], u1 = Zp[256 + r], u2 = Zp[512 + r], u3 = Zp[768 + r];
            fft4<0>(u0, u1, u2, u3);
            float2 w2 = cmul(w1, w1);
            float2 w3 = cmul(w2, w1);
            Zp[r] = u0;
            Zp[256 + r] = cmul(u1, w1);
            Zp[512 + r] = cmul(u2, w2);
            Zp[768 + r] = cmul(u3, w3);
            w1 = cmul(w1, jstep);
        }
    }
    {
        const int k4 = l >> 4, c = l & 15;
        const int nbase = 256 * k4 + c;
        float sn, cs;
        __sincosf(TWO_PI_F * (float)c * (1.f / 256.f), &sn, &cs);
        const float2 wc = make_float2(cs, -sn);
        float2 v[16];
#pragma unroll
        for (int b = 0; b < 16; b++) v[b] = Zp[nbase + 16 * b];
        fft16<0>(v);
        const int pbase = 272 * k4 + c;
        Zp[pbase] = V16(v, 0);
        float2 w = wc;
#pragma unroll
        for (int kb = 1; kb < 16; kb++) {
            Zp[pbase + 17 * kb] = cmul(V16(v, kb), w);
            w = cmul(w, wc);
        }
    }
    {
        const int pbase = 272 * (l >> 4) + 17 * (l & 15);
        float2 v[16];
#pragma unroll
        for (int c = 0; c < 16; c++) v[c] = Zp[pbase + c];
        fft16<0>(v);
#pragma unroll
        for (int kc = 0; kc < 16; kc++) Zp[pbase + kc] = V16(v, kc);
    }
}

// inverse wave-local 1024-pt FFT (mirror order, conjugate twiddles).
__device__ __forceinline__ void plane_inv(float2* __restrict__ Zp, int l) {
    {
        const int kb = l & 15;
        const int pbase = 272 * (l >> 4) + 17 * kb;
        float sn, cs;
        __sincosf(TWO_PI_F * (float)kb * (1.f / 256.f), &sn, &cs);
        const float2 wkb = make_float2(cs, sn);
        float2 v[16];
#pragma unroll
        for (int kc = 0; kc < 16; kc++) v[kc] = Zp[pbase + kc];
        fft16<1>(v);
        Zp[pbase] = V16(v, 0);
        float2 w = wkb;
#pragma unroll
        for (int nc = 1; nc < 16; nc++) {
            Zp[pbase + nc] = cmul(V16(v, nc), w);
            w = cmul(w, wkb);
        }
    }
    {
        const int k4 = l >> 4, nc = l & 15;
        const int pbase = 272 * k4 + nc;
        float sni, csi;
        __sincosf(TWO_PI_F * (float)(nc * k4) * (1.f / 1024.f), &sni, &csi);
        float2 t = make_float2(csi, sni);
        float sns, css;
        __sincosf(TWO_PI_F * (float)k4 * (1.f / 64.f), &sns, &css);
        const float2 st = make_float2(css, sns);
        float2 v[16];
#pragma unroll
        for (int kb = 0; kb < 16; kb++) v[kb] = Zp[pbase + 17 * kb];
        fft16<1>(v);
#pragma unroll
        for (int nb = 0; nb < 16; nb++) {
            Zp[pbase + 17 * nb] = cmul(V16(v, nb), t);
            t = cmul(t, st);
        }
    }
#pragma unroll
    for (int j = 0; j < 4; j++) {
        const int r = 64 * j + l;
        const int rp = r + (r >> 4);
        float2 u0 = Zp[rp], u1 = Zp[272 + rp], u2 = Zp[544 + rp], u3 = Zp[816 + rp];
        fft4<1>(u0, u1, u2, u3);
        Zp[rp] = u0; Zp[272 + rp] = u1; Zp[544 + rp] = u2; Zp[816 + rp] = u3;
    }
}

__device__ __forceinline__ float hinterp64(const float* f, int j) {
    float pos = ((float)j + 0.5f) * (1.0f / 256.0f) - 0.5f;
    pos = fminf(fmaxf(pos, 0.0f), 63.0f);
    int lo = (int)pos;
    int hi = min(lo + 1, 63);
    float w = pos - (float)lo;
    return f[lo] * (1.0f - w) + f[hi] * w;
}

// ---------------------------------------------------------------------------
// Kernel 1 (fused): prep (wave 0, fp64) + FFT filter. One block per batch.
// ---------------------------------------------------------------------------
__global__ __launch_bounds__(1024, 4) void fft_kernel(
    const float* __restrict__ packed, const float* __restrict__ freqs,
    const float* __restrict__ noise,
    unsigned long long* __restrict__ step, float* __restrict__ env,
    float* __restrict__ filt)
{
    __shared__ float2 Z[16 * PSTRIDE];   // 139,392 B
    __shared__ float fenv_s[64];
    __shared__ float amp_s[128];
    __shared__ double ampd_s[128];       // prep scratch (wave-0 only)
    const int bb = blockIdx.x;
    const int tid = threadIdx.x;
    const int wv = tid >> 6, l = tid & 63;

    // ---- prep: entirely within wave 0 (no extra barriers; DS in-order per wave)
    if (tid < 64) {
        const float* pk = packed + bb * 464;
        // softmax(sigmoid(p[0:128])) dot freqs, via in-wave shuffle reduce
        double e0 = exp(dsig((double)pk[tid]));
        double e1 = exp(dsig((double)pk[tid + 64]));
        double num = e0 * (double)freqs[tid] + e1 * (double)freqs[tid + 64];
        double den = e0 + e1;
#pragma unroll
        for (int off = 32; off > 0; off >>= 1) {
            num += __shfl_down(num, off);
            den += __shfl_down(den, off);
        }
        num = __shfl(num, 0);
        den = __shfl(den, 0);

        // amp (both halves), fenv
        double a0 = dsig((double)pk[256 + tid]) * 2.0 - 1.0;
        double a1 = dsig((double)pk[256 + 64 + tid]) * 2.0 - 1.0;
        ampd_s[tid] = a0; ampd_s[tid + 64] = a1;
        amp_s[tid] = (float)a0; amp_s[tid + 64] = (float)a1;
        fenv_s[tid] = (float)dsig((double)pk[400 + tid]);

        if (tid < 8) {
            const double NYQ = 11025.0;
            const double MIN_F0 = 40.0 / NYQ;
            const double MAX_F0 = 3000.0 / NYQ;
            const double F0_SPAN = MAX_F0 - MIN_F0;
            double f0 = num / den;
            double F = f0 * NYQ;
            double G = MIN_F0 + F * F0_SPAN;
            double oscf = G * (double)(tid + 1);
            double r = oscf / NYQ * M_PI;
            double rv = r / (2.0 * M_PI);
            rv -= floor(rv);
            step[bb * 8 + tid] = (unsigned long long)(rv * 18446744073709551616.0);

            double ha = dsig((double)pk[384 + tid]);
            double hd = 0.9 + dsig((double)pk[392 + tid]) * (1.0 - 0.9);
            double cur = 0.0;
            float* eo = env + (size_t)(bb * 8 + tid) * 128;
            for (int fr = 0; fr < 128; fr++) {
                cur = cur + ampd_s[fr] * ha;
                cur = fmin(fmax(cur, 0.0), 1.0);
                eo[fr] = (float)cur;
                cur *= hd;
            }
        }
    }

    const float2* nz = (const float2*)(noise + (size_t)bb * NSAMP);

    // ---- forward outer: in-thread fft16 over n1 (stride 1024), scatter to planes
    {
        float2 v[16];
#pragma unroll
        for (int a = 0; a < 16; a++) {
            float2 t = nz[a * 1024 + tid];
            v[a] = make_float2(t.x * 2.f - 1.f, t.y * 2.f - 1.f);
        }
        fft16<0>(v);
        float sn, cs;
        __sincosf(TWO_PI_F * (float)tid * (1.f / 16384.f), &sn, &cs);
        const float2 ws = make_float2(cs, -sn);
        Z[tid] = V16(v, 0);
        float2 w = ws;
#pragma unroll
        for (int k1 = 1; k1 < 16; k1++) {
            Z[k1 * PSTRIDE + tid] = cmul(V16(v, k1), w);
            w = cmul(w, ws);
        }
    }
    __syncthreads();

    plane_fwd(Z + wv * PSTRIDE, l);     // wave-local, no barriers
    __syncthreads();

    // ---- spectral combine (recurrence twiddles)
    const float invM = 1.0f / (float)MHALF;
    {
        float sn0, cs0;
        __sincosf((float)M_PI * (float)tid * (1.f / 16384.f), &sn0, &cs0);
        float2 t = make_float2(cs0, sn0);
        const float2 tstep = make_float2(0.98078528040323f, 0.19509032201613f); // e^{+i pi/16}
        for (int k = tid; k <= 8192; k += 1024) {
            if (k == 0) {
                int i0 = zaddr(0);
                float2 Z0 = Z[i0];
                float Y0 = (Z0.x + Z0.y) * hinterp64(fenv_s, 0);
                float vv = Y0 * 0.5f * invM;
                Z[i0] = make_float2(vv, vv);
            } else if (k == 8192) {
                int i8 = zaddr(8192);
                float s = hinterp64(fenv_s, 8192) * invM;
                float2 Zk = Z[i8];
                Z[i8] = make_float2(Zk.x * s, Zk.y * s);
            } else {
                int ik = zaddr(k), imk = zaddr(16384 - k);
                float2 Zk = Z[ik], Zm = Z[imk];
                float Ex = 0.5f * (Zk.x + Zm.x);
                float Ey = 0.5f * (Zk.y - Zm.y);
                float Ox = 0.5f * (Zk.y + Zm.y);
                float Oy = -0.5f * (Zk.x - Zm.x);
                float cs = t.x, sn = t.y;
                float Xkx = Ex + cs * Ox + sn * Oy;
                float Xky = Ey + cs * Oy - sn * Ox;
                float Xmx = Ex - cs * Ox - sn * Oy;
                float Xmy = -Ey + cs * Oy - sn * Ox;
                float Hk = hinterp64(fenv_s, k);
                float Hm = hinterp64(fenv_s, 16384 - k);
                float Ykx = Xkx * Hk, Yky = Xky * Hk;
                float Ymx = Xmx * Hm, Ymy = Xmy * Hm;
                float Er = 0.5f * (Ykx + Ymx);
                float Ei = 0.5f * (Yky - Ymy);
                float Pr = 0.5f * (Ykx - Ymx);
                float Pi = 0.5f * (Yky + Ymy);
                float Oyx = Pr * cs - Pi * sn;
                float Oyy = Pr * sn + Pi * cs;
                Z[ik]  = make_float2((Er - Oyy) * invM, (Ei + Oyx) * invM);
                Z[imk] = make_float2((Er + Oyy) * invM, (-Ei + Oyx) * invM);
            }
            t = cmul(t, tstep);
        }
    }
    __syncthreads();

    plane_inv(Z + wv * PSTRIDE, l);     // wave-local, no barriers
    __syncthreads();

    // ---- inverse outer: gather across planes, twiddle, fft16, amp, store
    {
        const int tp = tid + (tid >> 4);
        float2 v[16];
#pragma unroll
        for (int k1 = 0; k1 < 16; k1++) v[k1] = Z[k1 * PSTRIDE + tp];
        float sn, cs;
        __sincosf(TWO_PI_F * (float)tid * (1.f / 16384.f), &sn, &cs);
        const float2 wg = make_float2(cs, sn);
        float2 w = wg;
#pragma unroll
        for (int k1 = 1; k1 < 16; k1++) {
            v[k1] = cmul(v[k1], w);
            w = cmul(w, wg);
        }
        fft16<1>(v);

        float2* fo = (float2*)(filt + (size_t)bb * NSAMP);
#pragma unroll
        for (int m = 0; m < 16; m++) {
            float2 y = V16(v, m);
            int A = m * 1024 + tid;
            int s0 = 2 * A;
            float p0 = ((float)s0 + 0.5f) * (1.0f / 256.0f) - 0.5f;
            float p1 = p0 + (1.0f / 256.0f);
            p0 = fminf(fmaxf(p0, 0.0f), 127.0f);
            p1 = fminf(fmaxf(p1, 0.0f), 127.0f);
            int l0 = (int)p0, l1 = (int)p1;
            int h0 = min(l0 + 1, 127), h1 = min(l1 + 1, 127);
            float w0a = p0 - (float)l0, w1a = p1 - (float)l1;
            float a0 = amp_s[l0] * (1.0f - w0a) + amp_s[h0] * w0a;
            float a1 = amp_s[l1] * (1.0f - w1a) + amp_s[h1] * w1a;
            a0 = fminf(fmaxf(a0, 0.0f), 1.0f);
            a1 = fminf(fmaxf(a1, 0.0f), 1.0f);
            fo[A] = make_float2(y.x * a0, y.y * a1);
        }
    }
}

// ---------------------------------------------------------------------------
// Kernel 2: final synthesis — Q0.64 phase seed + float fract-recurrence + v_sin.
// ---------------------------------------------------------------------------
__global__ __launch_bounds__(256) void synth_kernel(
    const unsigned long long* __restrict__ step, const float* __restrict__ env,
    const float* __restrict__ filt, float* __restrict__ out)
{
    const int chunk = blockIdx.x;   // 0..31
    const int g = blockIdx.y;       // 0..31
    const int tid = threadIdx.x;
    __shared__ float env_s[64 * 128];
    __shared__ unsigned long long step_s[64];

    const float* eg = env + (size_t)g * 64 * 128;
    for (int i = tid; i < 64 * 128; i += 256) env_s[i] = eg[i];
    if (tid < 64) step_s[tid] = step[g * 64 + tid];
    __syncthreads();

    const int s0 = chunk * 1024 + tid * 4;

    float4 aF = make_float4(0.f, 0.f, 0.f, 0.f);
#pragma unroll
    for (int e = 0; e < 8; e++) {
        const float4 f = *(const float4*)(filt + ((size_t)(g * 8 + e)) * NSAMP + s0);
        aF.x += f.x; aF.y += f.y; aF.z += f.z; aF.w += f.w;
    }

    float c0v[4], c1v[4], c2v[4];
    int lo0;
    {
        float pos0 = ((float)s0 + 0.5f) * (1.0f / 256.0f) - 0.5f;
        pos0 = fminf(fmaxf(pos0, 0.0f), 127.0f);
        lo0 = (int)pos0;
#pragma unroll
        for (int k = 0; k < 4; k++) {
            float pos = ((float)(s0 + k) + 0.5f) * (1.0f / 256.0f) - 0.5f;
            pos = fminf(fmaxf(pos, 0.0f), 127.0f);
            int lo = (int)pos;
            float w = pos - (float)lo;
            if (lo == lo0) { c0v[k] = 1.0f - w; c1v[k] = w;        c2v[k] = 0.0f; }
            else           { c0v[k] = 0.0f;     c1v[k] = 1.0f - w; c2v[k] = w;    }
        }
    }
    const int i1 = min(lo0 + 1, 127);
    int lo3b = lo0;
    {
        float pos = ((float)(s0 + 3) + 0.5f) * (1.0f / 256.0f) - 0.5f;
        pos = fminf(fmaxf(pos, 0.0f), 127.0f);
        lo3b = (int)pos;
    }
    const int i2 = min(lo3b + 1, 127);

    float a0 = 0.f, a1 = 0.f, a2 = 0.f, a3 = 0.f;
    const unsigned long long n0 = (unsigned long long)(unsigned)(s0 + 1);

#pragma unroll 8
    for (int idx = 0; idx < 64; idx++) {
        const unsigned long long st = step_s[idx];
        const unsigned long long p = st * n0;          // exact u64 seed (sample 0)
        const float stf = (float)(unsigned)(st >> 32) * 0x1p-32f;
        float fr = (float)(unsigned)(p >> 32) * 0x1p-32f;
        const float* er = env_s + (idx << 7);
        const float v0 = er[lo0], v1 = er[i1], v2 = er[i2];

        float ev, sn;

        sn = __builtin_amdgcn_sinf(fr);
        ev = fmaf(v0, c0v[0], fmaf(v1, c1v[0], v2 * c2v[0]));
        a0 = fmaf(ev, sn, a0);
        fr = __builtin_amdgcn_fractf(fr + stf);

        sn = __builtin_amdgcn_sinf(fr);
        ev = fmaf(v0, c0v[1], fmaf(v1, c1v[1], v2 * c2v[1]));
        a1 = fmaf(ev, sn, a1);
        fr = __builtin_amdgcn_fractf(fr + stf);

        sn = __builtin_amdgcn_sinf(fr);
        ev = fmaf(v0, c0v[2], fmaf(v1, c1v[2], v2 * c2v[2]));
        a2 = fmaf(ev, sn, a2);
        fr = __builtin_amdgcn_fractf(fr + stf);

        sn = __builtin_amdgcn_sinf(fr);
        ev = fmaf(v0, c0v[3], fmaf(v1, c1v[3], v2 * c2v[3]));
        a3 = fmaf(ev, sn, a3);
    }

    float4 r;
    r.x = a0 + 8.0f * aF.x;
    r.y = a1 + 8.0f * aF.y;
    r.z = a2 + 8.0f * aF.z;
    r.w = a3 + 8.0f * aF.w;
    *(float4*)(out + (size_t)g * NSAMP + s0) = r;
}

extern "C" void kernel_launch(void* const* d_in, const int* in_sizes, int n_in,
                              void* d_out, int out_size, void* d_ws, size_t ws_size,
                              hipStream_t stream)
{
    (void)in_sizes; (void)n_in; (void)out_size; (void)ws_size;
    const float* packed = (const float*)d_in[0];
    const float* freqs  = (const float*)d_in[1];
    const float* noise  = (const float*)d_in[2];
    float* out = (float*)d_out;
    char* ws = (char*)d_ws;

    unsigned long long* step = (unsigned long long*)(ws);
    float* env  = (float*)(ws + 16384);
    float* filt = (float*)(ws + 16384 + 1048576 + 131072 + 65536);

    hipLaunchKernelGGL(fft_kernel, dim3(256), dim3(1024), 0, stream,
                       packed, freqs, noise, step, env, filt);
    hipLaunchKernelGGL(synth_kernel, dim3(32, 32), dim3(256), 0, stream,
                       step, env, filt, out);
}

// Round 9
// 122.114 us; speedup vs baseline: 1.3410x; 1.1019x over previous
//
#include <hip/hip_runtime.h>
#include <math.h>

#ifndef M_PI
#define M_PI 3.14159265358979323846
#endif

#define NSAMP 32768
#define MHALF 16384
#define TWO_PI_F 6.2831853071795864f
#define PSTRIDE 1089   // plane stride in v2; 1089&15==1 spreads planes across bank pairs

typedef float v2 __attribute__((ext_vector_type(2)));

__device__ __forceinline__ double dsig(double x) { return 1.0 / (1.0 + exp(-x)); }

// ---------------------------------------------------------------------------
// Complex helpers on packed 2-float vectors (lower to VOP3P v_pk_* on gfx950)
// ---------------------------------------------------------------------------
__device__ __forceinline__ v2 cmul(v2 a, v2 b) {
    // (a.x*b.x - a.y*b.y, a.x*b.y + a.y*b.x) = a.xx*b + {-a.y,a.y}*b.yx
    return a.xx * b + (v2){-a.y, a.y} * b.yx;
}

template<int INV>
__device__ __forceinline__ void fft4(v2& x0, v2& x1, v2& x2, v2& x3) {
    v2 s02 = x0 + x2;
    v2 d02 = x0 - x2;
    v2 s13 = x1 + x3;
    v2 d13 = x1 - x3;
    v2 j13 = INV ? (v2){-d13.y, d13.x} : (v2){d13.y, -d13.x};
    x0 = s02 + s13;
    x2 = s02 - s13;
    x1 = d02 + j13;
    x3 = d02 - j13;
}

// After fft16, natural-order output index c lives in register V16(v,c).
#define V16(v, c) v[((((c) & 3) << 2) | ((c) >> 2))]

template<int INV>
__device__ __forceinline__ void fft16(v2 v[16]) {
    const float s = INV ? 1.0f : -1.0f;
#pragma unroll
    for (int b = 0; b < 4; b++) fft4<INV>(v[b], v[4 + b], v[8 + b], v[12 + b]);
    v[5]  = cmul(v[5],  (v2){0.9238795325f,  s * 0.3826834324f});
    v[9]  = cmul(v[9],  (v2){0.7071067812f,  s * 0.7071067812f});
    v[13] = cmul(v[13], (v2){0.3826834324f,  s * 0.9238795325f});
    v[6]  = cmul(v[6],  (v2){0.7071067812f,  s * 0.7071067812f});
    v[10] = cmul(v[10], (v2){0.0f,           s * 1.0f});
    v[14] = cmul(v[14], (v2){-0.7071067812f, s * 0.7071067812f});
    v[7]  = cmul(v[7],  (v2){0.3826834324f,  s * 0.9238795325f});
    v[11] = cmul(v[11], (v2){-0.7071067812f, s * 0.7071067812f});
    v[15] = cmul(v[15], (v2){-0.9238795325f, s * -0.3826834324f});
#pragma unroll
    for (int p = 0; p < 4; p++) fft4<INV>(v[4 * p], v[4 * p + 1], v[4 * p + 2], v[4 * p + 3]);
}

// spectral k (0..16383) -> LDS index.
__device__ __forceinline__ int zaddr(int k) {
    int p = k & 15, k2 = k >> 4;
    int s = 256 * (k2 & 3) + 16 * ((k2 >> 2) & 15) + (k2 >> 6);
    return p * PSTRIDE + s + (s >> 4);
}

// forward wave-local 1024-pt FFT on plane (lane l).
__device__ __forceinline__ void plane_fwd(v2* __restrict__ Zp, int l) {
    {
        float sn, cs;
        __sincosf(TWO_PI_F * (float)l * (1.f / 1024.f), &sn, &cs);
        v2 w1 = (v2){cs, -sn};
        const v2 jstep = (v2){0.9238795325f, -0.3826834324f}; // e^{-2pi i/16}
#pragma unroll
        for (int j = 0; j < 4; j++) {
            const int r = 64 * j + l;
            v2 u0 = Zp[r], u1 = Zp[256 + r], u2 = Zp[512 + r], u3 = Zp[768 + r];
            fft4<0>(u0, u1, u2, u3);
            v2 w2 = cmul(w1, w1);
            v2 w3 = cmul(w2, w1);
            Zp[r] = u0;
            Zp[256 + r] = cmul(u1, w1);
            Zp[512 + r] = cmul(u2, w2);
            Zp[768 + r] = cmul(u3, w3);
            w1 = cmul(w1, jstep);
        }
    }
    {
        const int k4 = l >> 4, c = l & 15;
        const int nbase = 256 * k4 + c;
        float sn, cs;
        __sincosf(TWO_PI_F * (float)c * (1.f / 256.f), &sn, &cs);
        const v2 wc = (v2){cs, -sn};
        v2 v[16];
#pragma unroll
        for (int b = 0; b < 16; b++) v[b] = Zp[nbase + 16 * b];
        fft16<0>(v);
        const int pbase = 272 * k4 + c;
        Zp[pbase] = V16(v, 0);
        v2 w = wc;
#pragma unroll
        for (int kb = 1; kb < 16; kb++) {
            Zp[pbase + 17 * kb] = cmul(V16(v, kb), w);
            w = cmul(w, wc);
        }
    }
    {
        const int pbase = 272 * (l >> 4) + 17 * (l & 15);
        v2 v[16];
#pragma unroll
        for (int c = 0; c < 16; c++) v[c] = Zp[pbase + c];
        fft16<0>(v);
#pragma unroll
        for (int kc = 0; kc < 16; kc++) Zp[pbase + kc] = V16(v, kc);
    }
}

// inverse wave-local 1024-pt FFT (mirror order, conjugate twiddles).
__device__ __forceinline__ void plane_inv(v2* __restrict__ Zp, int l) {
    {
        const int kb = l & 15;
        const int pbase = 272 * (l >> 4) + 17 * kb;
        float sn, cs;
        __sincosf(TWO_PI_F * (float)kb * (1.f / 256.f), &sn, &cs);
        const v2 wkb = (v2){cs, sn};
        v2 v[16];
#pragma unroll
        for (int kc = 0; kc < 16; kc++) v[kc] = Zp[pbase + kc];
        fft16<1>(v);
        Zp[pbase] = V16(v, 0);
        v2 w = wkb;
#pragma unroll
        for (int nc = 1; nc < 16; nc++) {
            Zp[pbase + nc] = cmul(V16(v, nc), w);
            w = cmul(w, wkb);
        }
    }
    {
        const int k4 = l >> 4, nc = l & 15;
        const int pbase = 272 * k4 + nc;
        float sni, csi;
        __sincosf(TWO_PI_F * (float)(nc * k4) * (1.f / 1024.f), &sni, &csi);
        v2 t = (v2){csi, sni};
        float sns, css;
        __sincosf(TWO_PI_F * (float)k4 * (1.f / 64.f), &sns, &css);
        const v2 st = (v2){css, sns};
        v2 v[16];
#pragma unroll
        for (int kb = 0; kb < 16; kb++) v[kb] = Zp[pbase + 17 * kb];
        fft16<1>(v);
#pragma unroll
        for (int nb = 0; nb < 16; nb++) {
            Zp[pbase + 17 * nb] = cmul(V16(v, nb), t);
            t = cmul(t, st);
        }
    }
#pragma unroll
    for (int j = 0; j < 4; j++) {
        const int r = 64 * j + l;
        const int rp = r + (r >> 4);
        v2 u0 = Zp[rp], u1 = Zp[272 + rp], u2 = Zp[544 + rp], u3 = Zp[816 + rp];
        fft4<1>(u0, u1, u2, u3);
        Zp[rp] = u0; Zp[272 + rp] = u1; Zp[544 + rp] = u2; Zp[816 + rp] = u3;
    }
}

__device__ __forceinline__ float hinterp64(const float* f, int j) {
    float pos = ((float)j + 0.5f) * (1.0f / 256.0f) - 0.5f;
    pos = fminf(fmaxf(pos, 0.0f), 63.0f);
    int lo = (int)pos;
    int hi = min(lo + 1, 63);
    float w = pos - (float)lo;
    return f[lo] * (1.0f - w) + f[hi] * w;
}

// ---------------------------------------------------------------------------
// Kernel 1 (fused): prep (wave 0, fp64) + FFT filter. One block per batch.
// ---------------------------------------------------------------------------
__global__ __launch_bounds__(1024, 4) void fft_kernel(
    const float* __restrict__ packed, const float* __restrict__ freqs,
    const float* __restrict__ noise,
    unsigned long long* __restrict__ step, float* __restrict__ env,
    float* __restrict__ filt)
{
    __shared__ v2 Z[16 * PSTRIDE];   // 139,392 B
    __shared__ float fenv_s[64];
    __shared__ float amp_s[128];
    __shared__ double ampd_s[128];       // prep scratch (wave-0 only)
    const int bb = blockIdx.x;
    const int tid = threadIdx.x;
    const int wv = tid >> 6, l = tid & 63;

    // ---- prep: entirely within wave 0 (no extra barriers; DS in-order per wave)
    if (tid < 64) {
        const float* pk = packed + bb * 464;
        double e0 = exp(dsig((double)pk[tid]));
        double e1 = exp(dsig((double)pk[tid + 64]));
        double num = e0 * (double)freqs[tid] + e1 * (double)freqs[tid + 64];
        double den = e0 + e1;
#pragma unroll
        for (int off = 32; off > 0; off >>= 1) {
            num += __shfl_down(num, off);
            den += __shfl_down(den, off);
        }
        num = __shfl(num, 0);
        den = __shfl(den, 0);

        double a0 = dsig((double)pk[256 + tid]) * 2.0 - 1.0;
        double a1 = dsig((double)pk[256 + 64 + tid]) * 2.0 - 1.0;
        ampd_s[tid] = a0; ampd_s[tid + 64] = a1;
        amp_s[tid] = (float)a0; amp_s[tid + 64] = (float)a1;
        fenv_s[tid] = (float)dsig((double)pk[400 + tid]);

        if (tid < 8) {
            const double NYQ = 11025.0;
            const double MIN_F0 = 40.0 / NYQ;
            const double MAX_F0 = 3000.0 / NYQ;
            const double F0_SPAN = MAX_F0 - MIN_F0;
            double f0 = num / den;
            double F = f0 * NYQ;
            double G = MIN_F0 + F * F0_SPAN;
            double oscf = G * (double)(tid + 1);
            double r = oscf / NYQ * M_PI;
            double rv = r / (2.0 * M_PI);
            rv -= floor(rv);
            step[bb * 8 + tid] = (unsigned long long)(rv * 18446744073709551616.0);

            double ha = dsig((double)pk[384 + tid]);
            double hd = 0.9 + dsig((double)pk[392 + tid]) * (1.0 - 0.9);
            double cur = 0.0;
            float* eo = env + (size_t)(bb * 8 + tid) * 128;
            for (int fr = 0; fr < 128; fr++) {
                cur = cur + ampd_s[fr] * ha;
                cur = fmin(fmax(cur, 0.0), 1.0);
                eo[fr] = (float)cur;
                cur *= hd;
            }
        }
    }

    const v2* nz = (const v2*)(noise + (size_t)bb * NSAMP);

    // ---- forward outer: in-thread fft16 over n1 (stride 1024), scatter to planes
    {
        v2 v[16];
#pragma unroll
        for (int a = 0; a < 16; a++) {
            v2 t = nz[a * 1024 + tid];
            v[a] = t * 2.f - 1.f;
        }
        fft16<0>(v);
        float sn, cs;
        __sincosf(TWO_PI_F * (float)tid * (1.f / 16384.f), &sn, &cs);
        const v2 ws = (v2){cs, -sn};
        Z[tid] = V16(v, 0);
        v2 w = ws;
#pragma unroll
        for (int k1 = 1; k1 < 16; k1++) {
            Z[k1 * PSTRIDE + tid] = cmul(V16(v, k1), w);
            w = cmul(w, ws);
        }
    }
    __syncthreads();

    plane_fwd(Z + wv * PSTRIDE, l);     // wave-local, no barriers
    __syncthreads();

    // ---- spectral combine (recurrence twiddles)
    const float invM = 1.0f / (float)MHALF;
    {
        float sn0, cs0;
        __sincosf((float)M_PI * (float)tid * (1.f / 16384.f), &sn0, &cs0);
        v2 t = (v2){cs0, sn0};
        const v2 tstep = (v2){0.98078528040323f, 0.19509032201613f}; // e^{+i pi/16}
        for (int k = tid; k <= 8192; k += 1024) {
            if (k == 0) {
                int i0 = zaddr(0);
                v2 Z0 = Z[i0];
                float Y0 = (Z0.x + Z0.y) * hinterp64(fenv_s, 0);
                float vv = Y0 * 0.5f * invM;
                Z[i0] = (v2){vv, vv};
            } else if (k == 8192) {
                int i8 = zaddr(8192);
                float s = hinterp64(fenv_s, 8192) * invM;
                Z[i8] = Z[i8] * s;
            } else {
                int ik = zaddr(k), imk = zaddr(16384 - k);
                v2 Zk = Z[ik], Zm = Z[imk];
                float Ex = 0.5f * (Zk.x + Zm.x);
                float Ey = 0.5f * (Zk.y - Zm.y);
                float Ox = 0.5f * (Zk.y + Zm.y);
                float Oy = -0.5f * (Zk.x - Zm.x);
                float cs = t.x, sn = t.y;
                float Xkx = Ex + cs * Ox + sn * Oy;
                float Xky = Ey + cs * Oy - sn * Ox;
                float Xmx = Ex - cs * Ox - sn * Oy;
                float Xmy = -Ey + cs * Oy - sn * Ox;
                float Hk = hinterp64(fenv_s, k);
                float Hm = hinterp64(fenv_s, 16384 - k);
                float Ykx = Xkx * Hk, Yky = Xky * Hk;
                float Ymx = Xmx * Hm, Ymy = Xmy * Hm;
                float Er = 0.5f * (Ykx + Ymx);
                float Ei = 0.5f * (Yky - Ymy);
                float Pr = 0.5f * (Ykx - Ymx);
                float Pi = 0.5f * (Yky + Ymy);
                float Oyx = Pr * cs - Pi * sn;
                float Oyy = Pr * sn + Pi * cs;
                Z[ik]  = (v2){(Er - Oyy) * invM, (Ei + Oyx) * invM};
                Z[imk] = (v2){(Er + Oyy) * invM, (-Ei + Oyx) * invM};
            }
            t = cmul(t, tstep);
        }
    }
    __syncthreads();

    plane_inv(Z + wv * PSTRIDE, l);     // wave-local, no barriers
    __syncthreads();

    // ---- inverse outer: gather across planes, twiddle, fft16, amp, store
    {
        const int tp = tid + (tid >> 4);
        v2 v[16];
#pragma unroll
        for (int k1 = 0; k1 < 16; k1++) v[k1] = Z[k1 * PSTRIDE + tp];
        float sn, cs;
        __sincosf(TWO_PI_F * (float)tid * (1.f / 16384.f), &sn, &cs);
        const v2 wg = (v2){cs, sn};
        v2 w = wg;
#pragma unroll
        for (int k1 = 1; k1 < 16; k1++) {
            v[k1] = cmul(v[k1], w);
            w = cmul(w, wg);
        }
        fft16<1>(v);

        v2* fo = (v2*)(filt + (size_t)bb * NSAMP);
#pragma unroll
        for (int m = 0; m < 16; m++) {
            v2 y = V16(v, m);
            int A = m * 1024 + tid;
            int s0 = 2 * A;
            float p0 = ((float)s0 + 0.5f) * (1.0f / 256.0f) - 0.5f;
            float p1 = p0 + (1.0f / 256.0f);
            p0 = fminf(fmaxf(p0, 0.0f), 127.0f);
            p1 = fminf(fmaxf(p1, 0.0f), 127.0f);
            int l0 = (int)p0, l1 = (int)p1;
            int h0 = min(l0 + 1, 127), h1 = min(l1 + 1, 127);
            float w0a = p0 - (float)l0, w1a = p1 - (float)l1;
            float a0 = amp_s[l0] * (1.0f - w0a) + amp_s[h0] * w0a;
            float a1 = amp_s[l1] * (1.0f - w1a) + amp_s[h1] * w1a;
            a0 = fminf(fmaxf(a0, 0.0f), 1.0f);
            a1 = fminf(fmaxf(a1, 0.0f), 1.0f);
            fo[A] = (v2){y.x * a0, y.y * a1};
        }
    }
}

// ---------------------------------------------------------------------------
// Kernel 2: final synthesis — Q0.64 phase seed + float fract-recurrence + v_sin.
// ---------------------------------------------------------------------------
__global__ __launch_bounds__(256) void synth_kernel(
    const unsigned long long* __restrict__ step, const float* __restrict__ env,
    const float* __restrict__ filt, float* __restrict__ out)
{
    const int chunk = blockIdx.x;   // 0..31
    const int g = blockIdx.y;       // 0..31
    const int tid = threadIdx.x;
    __shared__ float env_s[64 * 128];
    __shared__ unsigned long long step_s[64];

    const float* eg = env + (size_t)g * 64 * 128;
    for (int i = tid; i < 64 * 128; i += 256) env_s[i] = eg[i];
    if (tid < 64) step_s[tid] = step[g * 64 + tid];
    __syncthreads();

    const int s0 = chunk * 1024 + tid * 4;

    float4 aF = make_float4(0.f, 0.f, 0.f, 0.f);
#pragma unroll
    for (int e = 0; e < 8; e++) {
        const float4 f = *(const float4*)(filt + ((size_t)(g * 8 + e)) * NSAMP + s0);
        aF.x += f.x; aF.y += f.y; aF.z += f.z; aF.w += f.w;
    }

    float c0v[4], c1v[4], c2v[4];
    int lo0;
    {
        float pos0 = ((float)s0 + 0.5f) * (1.0f / 256.0f) - 0.5f;
        pos0 = fminf(fmaxf(pos0, 0.0f), 127.0f);
        lo0 = (int)pos0;
#pragma unroll
        for (int k = 0; k < 4; k++) {
            float pos = ((float)(s0 + k) + 0.5f) * (1.0f / 256.0f) - 0.5f;
            pos = fminf(fmaxf(pos, 0.0f), 127.0f);
            int lo = (int)pos;
            float w = pos - (float)lo;
            if (lo == lo0) { c0v[k] = 1.0f - w; c1v[k] = w;        c2v[k] = 0.0f; }
            else           { c0v[k] = 0.0f;     c1v[k] = 1.0f - w; c2v[k] = w;    }
        }
    }
    const int i1 = min(lo0 + 1, 127);
    int lo3b = lo0;
    {
        float pos = ((float)(s0 + 3) + 0.5f) * (1.0f / 256.0f) - 0.5f;
        pos = fminf(fmaxf(pos, 0.0f), 127.0f);
        lo3b = (int)pos;
    }
    const int i2 = min(lo3b + 1, 127);

    float a0 = 0.f, a1 = 0.f, a2 = 0.f, a3 = 0.f;
    const unsigned long long n0 = (unsigned long long)(unsigned)(s0 + 1);

#pragma unroll 8
    for (int idx = 0; idx < 64; idx++) {
        const unsigned long long st = step_s[idx];
        const unsigned long long p = st * n0;          // exact u64 seed (sample 0)
        const float stf = (float)(unsigned)(st >> 32) * 0x1p-32f;
        float fr = (float)(unsigned)(p >> 32) * 0x1p-32f;
        const float* er = env_s + (idx << 7);
        const float v0 = er[lo0], v1 = er[i1], v2 = er[i2];

        float ev, sn;

        sn = __builtin_amdgcn_sinf(fr);
        ev = fmaf(v0, c0v[0], fmaf(v1, c1v[0], v2 * c2v[0]));
        a0 = fmaf(ev, sn, a0);
        fr = __builtin_amdgcn_fractf(fr + stf);

        sn = __builtin_amdgcn_sinf(fr);
        ev = fmaf(v0, c0v[1], fmaf(v1, c1v[1], v2 * c2v[1]));
        a1 = fmaf(ev, sn, a1);
        fr = __builtin_amdgcn_fractf(fr + stf);

        sn = __builtin_amdgcn_sinf(fr);
        ev = fmaf(v0, c0v[2], fmaf(v1, c1v[2], v2 * c2v[2]));
        a2 = fmaf(ev, sn, a2);
        fr = __builtin_amdgcn_fractf(fr + stf);

        sn = __builtin_amdgcn_sinf(fr);
        ev = fmaf(v0, c0v[3], fmaf(v1, c1v[3], v2 * c2v[3]));
        a3 = fmaf(ev, sn, a3);
    }

    float4 r;
    r.x = a0 + 8.0f * aF.x;
    r.y = a1 + 8.0f * aF.y;
    r.z = a2 + 8.0f * aF.z;
    r.w = a3 + 8.0f * aF.w;
    *(float4*)(out + (size_t)g * NSAMP + s0) = r;
}

extern "C" void kernel_launch(void* const* d_in, const int* in_sizes, int n_in,
                              void* d_out, int out_size, void* d_ws, size_t ws_size,
                              hipStream_t stream)
{
    (void)in_sizes; (void)n_in; (void)out_size; (void)ws_size;
    const float* packed = (const float*)d_in[0];
    const float* freqs  = (const float*)d_in[1];
    const float* noise  = (const float*)d_in[2];
    float* out = (float*)d_out;
    char* ws = (char*)d_ws;

    unsigned long long* step = (unsigned long long*)(ws);
    float* env  = (float*)(ws + 16384);
    float* filt = (float*)(ws + 16384 + 1048576 + 131072 + 65536);

    hipLaunchKernelGGL(fft_kernel, dim3(256), dim3(1024), 0, stream,
                       packed, freqs, noise, step, env, filt);
    hipLaunchKernelGGL(synth_kernel, dim3(32, 32), dim3(256), 0, stream,
                       step, env, filt, out);
}